// Round 1
// baseline (1820.438 us; speedup 1.0000x reference)
//
#include <hip/hip_runtime.h>

#define T_ 3
#define NPER 20000
#define NN 60000
#define EE 480000
#define BB 200000
#define RR 5

__device__ inline unsigned fkey(float f){ unsigned u = __float_as_uint(f); return (u & 0x80000000u) ? ~u : (u | 0x80000000u); }
__device__ inline float fdecode(unsigned k){ unsigned u = (k & 0x80000000u) ? (k & 0x7fffffffu) : ~k; return __uint_as_float(u); }
__device__ inline float lrelu(float x){ return x > 0.f ? x : 0.2f*x; }
__device__ inline float eluf(float x){ return x > 0.f ? x : (__expf(x) - 1.f); }

// ---- input FC: nt[n,o] = feats[n,:] @ fc_w[t] + fc_b[t] ----
__global__ void k_input_fc(const float* __restrict__ feats, const float* __restrict__ fcw,
                           const float* __restrict__ fcb, float* __restrict__ nt) {
    int gid = blockIdx.x*256 + threadIdx.x;
    int n = gid >> 5, o = gid & 31;
    if (n >= NN) return;
    int t = n / NPER;
    const float* fr = feats + (size_t)n*64;
    const float* w = fcw + t*(64*32);
    float acc = fcb[t*32+o];
    #pragma unroll
    for (int k = 0; k < 64; ++k) acc += fr[k] * w[k*32+o];
    nt[n*32+o] = acc;
}

// ---- emb0: z[:,0:32] = aggr(l2n(slot-sparse h)) = nt/(3*||nt||) ----
__global__ void k_emb0(const float* __restrict__ nt, float* __restrict__ z) {
    int gid = blockIdx.x*256 + threadIdx.x;
    int n = gid >> 5, c = gid & 31;
    if (n >= NN) return;
    float v = nt[n*32+c];
    float ss = v*v;
    for (int off = 16; off; off >>= 1) ss += __shfl_xor(ss, off, 32);
    float nr = fmaxf(sqrtf(ss), 1e-12f);
    z[(size_t)n*128 + c] = v / (3.f*nr);
}

// ---- edge logit table [R,H]: one block per (r,h), 64 threads over d ----
__global__ void k_tab(const float* __restrict__ eemb, const float* __restrict__ fcw,
                      const float* __restrict__ fcb, const float* __restrict__ ae,
                      int H, float* __restrict__ tab) {
    int r = blockIdx.x / H, h = blockIdx.x % H, d = threadIdx.x;
    float acc = fcb[h*64+d];
    const float* er = eemb + r*64;
    #pragma unroll
    for (int k = 0; k < 64; ++k) acc += er[k] * fcw[k*(H*64) + h*64 + d];
    float v = acc * ae[h*64+d];
    for (int off = 32; off; off >>= 1) v += __shfl_xor(v, off, 64);
    if (d == 0) tab[r*H+h] = v;
}

// ---- layer0 f (compact [N,2,32]) + el/er; one wave per node ----
__global__ void k_f0(const float* __restrict__ nt, const float* __restrict__ w0,
                     const float* __restrict__ al, const float* __restrict__ ar,
                     float* __restrict__ f0, float* __restrict__ el, float* __restrict__ er) {
    int gid = blockIdx.x*256 + threadIdx.x;
    int n = gid >> 6, l = gid & 63;
    if (n >= NN) return;
    int t = n / NPER, h = l >> 5, d = l & 31;
    const float* ntp = nt + n*32;
    const float* wp = w0 + t*(32*64);
    float acc = 0.f;
    #pragma unroll
    for (int i = 0; i < 32; ++i) acc += ntp[i] * wp[i*64 + l];
    f0[(size_t)n*64+l] = acc;
    float pe = acc * al[h*96 + t*32 + d];
    float pr = acc * ar[h*96 + t*32 + d];
    for (int off = 16; off; off >>= 1) { pe += __shfl_xor(pe, off, 32); pr += __shfl_xor(pr, off, 32); }
    if (d == 0) { el[n*2+h] = pe; er[n*2+h] = pr; }
}

// ---- edge passes ----
__global__ void k_edge_max(const int* __restrict__ src, const int* __restrict__ dst, const int* __restrict__ et,
                           const float* __restrict__ el, const float* __restrict__ er, const float* __restrict__ tab,
                           int H, float* __restrict__ ebuf, unsigned int* __restrict__ mkey) {
    int idx = blockIdx.x*256 + threadIdx.x;
    if (idx >= EE*H) return;
    int e = idx / H, h = idx - e*H;
    int sN = src[e], dN = dst[e];
    float x = el[sN*H+h] + er[dN*H+h] + tab[et[e]*H+h];
    x = lrelu(x);
    ebuf[idx] = x;
    atomicMax(&mkey[dN*H+h], fkey(x));
}

__global__ void k_edge_expsum(const int* __restrict__ dst, int H, float* __restrict__ ebuf,
                              const unsigned int* __restrict__ mkey, float* __restrict__ s) {
    int idx = blockIdx.x*256 + threadIdx.x;
    if (idx >= EE*H) return;
    int e = idx / H, h = idx - e*H;
    int dN = dst[e];
    float ex = __expf(ebuf[idx] - fdecode(mkey[dN*H+h]));
    ebuf[idx] = ex;
    atomicAdd(&s[dN*H+h], ex);
}

// a = ex/(s+1e-9) [optionally mixed with res_attn]; overwrite ebuf; optionally store a0
__global__ void k_attn(const int* __restrict__ dst, int H, float* __restrict__ ebuf,
                       const float* __restrict__ s, const float* __restrict__ resat,
                       float* __restrict__ store0) {
    int idx = blockIdx.x*256 + threadIdx.x;
    if (idx >= EE*H) return;
    int e = idx / H, h = idx - e*H;
    int dN = dst[e];
    float a = ebuf[idx] / (s[dN*H+h] + 1e-9f);
    if (resat) a = a*0.95f + resat[idx]*0.05f;
    if (store0) store0[idx] = a;
    ebuf[idx] = a;
}

// ---- scatters ----
__global__ void k_scatter0(const int* __restrict__ src, const int* __restrict__ dst,
                           const float* __restrict__ ebuf, const float* __restrict__ f0,
                           float* __restrict__ rst) {
    int gid = blockIdx.x*256 + threadIdx.x;
    int e = gid >> 6, l = gid & 63;
    if (e >= EE) return;
    int h = l >> 5, d = l & 31;
    int sN = src[e], dN = dst[e];
    int ts = sN / NPER;
    float a = ebuf[e*2+h];
    atomicAdd(&rst[(size_t)dN*192 + h*96 + ts*32 + d], a * f0[(size_t)sN*64 + l]);
}

__global__ void k_scatter1(const int* __restrict__ src, const int* __restrict__ dst,
                           const float* __restrict__ ebuf, const float* __restrict__ f1,
                           float* __restrict__ rst) {
    int gid = blockIdx.x*256 + threadIdx.x;
    if (gid >= EE*192) return;
    int e = gid / 192, rem = gid - e*192;
    int h = rem / 96;
    int sN = src[e], dN = dst[e];
    float a = ebuf[e*2+h];
    atomicAdd(&rst[(size_t)dN*192 + rem], a * f1[(size_t)sN*192 + rem]);
}

__global__ void k_scatter2(const int* __restrict__ src, const int* __restrict__ dst,
                           const float* __restrict__ ebuf, const float* __restrict__ f2,
                           float* __restrict__ rst) {
    int gid = blockIdx.x*256 + threadIdx.x;
    if (gid >= EE*96) return;
    int e = gid / 96, k = gid - e*96;
    int sN = src[e], dN = dst[e];
    atomicAdd(&rst[(size_t)dN*96 + k], ebuf[e] * f2[(size_t)sN*96 + k]);
}

// ---- layer1 feat: f1[n,h*96+t*32+d] = sum_i h1[n, i/32, t*32+i%32] * w1[t,i,h*32+d] ----
__global__ void k_f1(const float* __restrict__ h1, const float* __restrict__ w1,
                     float* __restrict__ f1) {
    __shared__ float hrow[192];
    int n = blockIdx.x, tid = threadIdx.x;
    hrow[tid] = h1[(size_t)n*192 + tid];
    __syncthreads();
    int h = tid / 96, km = tid - h*96, t = km >> 5, d = km & 31, o = h*32 + d;
    const float* wp = w1 + t*(64*64);
    float acc = 0.f;
    #pragma unroll
    for (int i = 0; i < 64; ++i) acc += hrow[(i>>5)*96 + t*32 + (i&31)] * wp[i*64+o];
    f1[(size_t)n*192 + tid] = acc;
}

// ---- el/er for layer1 (heads=2, 192 values/node); one wave per node ----
__global__ void k_el1(const float* __restrict__ f1, const float* __restrict__ al,
                      const float* __restrict__ ar, float* __restrict__ el, float* __restrict__ er) {
    int gid = blockIdx.x*256 + threadIdx.x;
    int n = gid >> 6, l = gid & 63;
    if (n >= NN) return;
    const float* b = f1 + (size_t)n*192;
    float v0 = b[l], v1 = b[l+64], v2 = b[l+128];
    float pe0 = v0*al[l],     pr0 = v0*ar[l];
    float pe1 = v2*al[l+128], pr1 = v2*ar[l+128];
    float me = v1*al[l+64], mr = v1*ar[l+64];
    if (l < 32) { pe0 += me; pr0 += mr; } else { pe1 += me; pr1 += mr; }
    for (int off = 32; off; off >>= 1) {
        pe0 += __shfl_xor(pe0, off, 64); pr0 += __shfl_xor(pr0, off, 64);
        pe1 += __shfl_xor(pe1, off, 64); pr1 += __shfl_xor(pr1, off, 64);
    }
    if (l == 0) { el[n*2] = pe0; el[n*2+1] = pe1; er[n*2] = pr0; er[n*2+1] = pr1; }
}

// ---- layer2 feat + residual-init: fused (shares LDS-staged h2 row) ----
__global__ void k_f2res(const float* __restrict__ h2, const float* __restrict__ w2,
                        const float* __restrict__ rw, float* __restrict__ f2,
                        float* __restrict__ rst2) {
    __shared__ float hrow[384];
    int tid = threadIdx.x;
    int nb = blockIdx.x*2;
    for (int j = tid; j < 384; j += 192) hrow[j] = h2[(size_t)nb*192 + j];
    __syncthreads();
    int ln = tid / 96, km = tid - ln*96;
    int n = nb + ln;
    int t = km >> 5, d = km & 31;
    const float* hr = hrow + ln*192;
    float accf = 0.f, accr = 0.f;
    #pragma unroll
    for (int i = 0; i < 64; ++i) {
        float hv = hr[(i>>5)*96 + t*32 + (i&31)];
        accf += hv * w2[t*2048 + i*32 + d];
        accr += hv * rw[i*32 + d];
    }
    f2[(size_t)n*96+km] = accf;
    rst2[(size_t)n*96+km] = accr;
}

// ---- el/er for layer2 (heads=1, 96 values/node) ----
__global__ void k_el2(const float* __restrict__ f2, const float* __restrict__ al,
                      const float* __restrict__ ar, float* __restrict__ el, float* __restrict__ er) {
    int gid = blockIdx.x*256 + threadIdx.x;
    int n = gid >> 6, l = gid & 63;
    if (n >= NN) return;
    const float* b = f2 + (size_t)n*96;
    float v0 = b[l];
    float pe = v0*al[l], pr = v0*ar[l];
    if (l < 32) { float v1 = b[64+l]; pe += v1*al[64+l]; pr += v1*ar[64+l]; }
    for (int off = 32; off; off >>= 1) { pe += __shfl_xor(pe, off, 64); pr += __shfl_xor(pr, off, 64); }
    if (l == 0) { el[n] = pe; er[n] = pr; }
}

// ---- finalize layer 0/1: bias + elu (in place -> becomes h), emb -> z[:,zcol:zcol+32] ----
__global__ void k_final01(float* __restrict__ rst, const float* __restrict__ bias,
                          float* __restrict__ z, int zcol) {
    __shared__ float xs[2][96];
    __shared__ float sn[2];
    int tid = threadIdx.x;
    int ln = tid / 96, k = tid - ln*96;
    int n = blockIdx.x*2 + ln;
    if (tid < 2) sn[tid] = 0.f;
    float v0 = eluf(rst[(size_t)n*192 + k]      + bias[k]);
    float v1 = eluf(rst[(size_t)n*192 + 96 + k] + bias[96+k]);
    rst[(size_t)n*192 + k] = v0;
    rst[(size_t)n*192 + 96 + k] = v1;
    float x = 0.5f*(v0+v1);
    xs[ln][k] = x;
    __syncthreads();
    atomicAdd(&sn[ln], x*x);
    __syncthreads();
    float nr = fmaxf(sqrtf(sn[ln]), 1e-12f);
    if (k < 32) z[(size_t)n*128 + zcol + k] = (xs[ln][k] + xs[ln][32+k] + xs[ln][64+k]) / (3.f*nr);
}

// ---- finalize layer 2: bias, emb3 -> z[:,96:128] ----
__global__ void k_final2(const float* __restrict__ rst2, const float* __restrict__ bias,
                         float* __restrict__ z) {
    __shared__ float xs[2][96];
    __shared__ float sn[2];
    int tid = threadIdx.x;
    int ln = tid / 96, k = tid - ln*96;
    int n = blockIdx.x*2 + ln;
    if (tid < 2) sn[tid] = 0.f;
    float x = rst2[(size_t)n*96 + k] + bias[k];
    xs[ln][k] = x;
    __syncthreads();
    atomicAdd(&sn[ln], x*x);
    __syncthreads();
    float nr = fmaxf(sqrtf(sn[ln]), 1e-12f);
    if (k < 32) z[(size_t)n*128 + 96 + k] = (xs[ln][k] + xs[ln][32+k] + xs[ln][64+k]) / (3.f*nr);
}

// ---- DistMult: one wave per pair; lanes own columns j=l, l+64 (coalesced W rows) ----
__global__ void k_distmult(const float* __restrict__ z, const float* __restrict__ W,
                           const int* __restrict__ left, const int* __restrict__ right,
                           const int* __restrict__ mid, float* __restrict__ out) {
    __shared__ float sle[4][128];
    int tid = threadIdx.x;
    int w = tid >> 6, lane = tid & 63;
    int b = blockIdx.x*4 + w;
    if (b >= BB) return;     // BB % 4 == 0: never taken, whole waves uniform
    int li = left[b], rn = right[b], r = mid[b];
    const float* lep = z + (size_t)li*128;
    const float* rip = z + (size_t)rn*128;
    sle[w][lane]    = lep[lane];
    sle[w][lane+64] = lep[lane+64];
    __syncthreads();
    const float* Wp = W + (size_t)r*16384;
    float accA = 0.f, accB = 0.f;
    #pragma unroll 4
    for (int i = 0; i < 128; ++i) {
        float le = sle[w][i];
        accA += le * Wp[i*128 + lane];
        accB += le * Wp[i*128 + 64 + lane];
    }
    float part = rip[lane]*accA + rip[lane+64]*accB;
    for (int off = 32; off; off >>= 1) part += __shfl_xor(part, off, 64);
    if (lane == 0) out[b] = part;
}

extern "C" void kernel_launch(void* const* d_in, const int* in_sizes, int n_in,
                              void* d_out, int out_size, void* d_ws, size_t ws_size,
                              hipStream_t stream) {
    const float* feats = (const float*)d_in[0];
    const float* fc_w  = (const float*)d_in[1];
    const float* fc_b  = (const float*)d_in[2];
    const float* w0    = (const float*)d_in[3];
    const float* al0   = (const float*)d_in[4];
    const float* ar0   = (const float*)d_in[5];
    const float* b0    = (const float*)d_in[6];
    const float* eemb0 = (const float*)d_in[7];
    const float* fce_w0= (const float*)d_in[8];
    const float* fce_b0= (const float*)d_in[9];
    const float* ae0   = (const float*)d_in[10];
    const float* w1    = (const float*)d_in[11];
    const float* al1   = (const float*)d_in[12];
    const float* ar1   = (const float*)d_in[13];
    const float* b1    = (const float*)d_in[14];
    const float* eemb1 = (const float*)d_in[15];
    const float* fce_w1= (const float*)d_in[16];
    const float* fce_b1= (const float*)d_in[17];
    const float* ae1   = (const float*)d_in[18];
    const float* w2    = (const float*)d_in[19];
    const float* al2   = (const float*)d_in[20];
    const float* ar2   = (const float*)d_in[21];
    const float* b2    = (const float*)d_in[22];
    const float* eemb2 = (const float*)d_in[23];
    const float* fce_w2= (const float*)d_in[24];
    const float* fce_b2= (const float*)d_in[25];
    const float* ae2   = (const float*)d_in[26];
    const float* resw2 = (const float*)d_in[27];
    const float* Wdm   = (const float*)d_in[28];
    const int* src   = (const int*)d_in[29];
    const int* dst   = (const int*)d_in[30];
    const int* etype = (const int*)d_in[31];
    const int* left  = (const int*)d_in[32];
    const int* right = (const int*)d_in[33];
    const int* mid   = (const int*)d_in[34];
    float* out = (float*)d_out;

    char* ws = (char*)d_ws;
    size_t off = 0;
    auto alloc = [&](size_t bytes) -> void* {
        void* p = ws + off;
        off = (off + bytes + 255) & ~(size_t)255;
        return p;
    };
    float* nt   = (float*)alloc((size_t)NN*32*4);
    float* z    = (float*)alloc((size_t)NN*128*4);
    float* fbuf = (float*)alloc((size_t)NN*192*4);   // f0 / f1 / f2 (reused)
    float* r0   = (float*)alloc((size_t)NN*192*4);   // rst0 -> h1
    float* r1   = (float*)alloc((size_t)NN*192*4);   // rst1 -> h2
    float* r2   = (float*)alloc((size_t)NN*96*4);    // rst2 -> logits
    float* el   = (float*)alloc((size_t)NN*2*4);
    float* er   = (float*)alloc((size_t)NN*2*4);
    unsigned int* mkey = (unsigned int*)alloc((size_t)NN*2*4);
    float* sbuf = (float*)alloc((size_t)NN*2*4);
    float* ebuf = (float*)alloc((size_t)EE*2*4);
    float* a0b  = (float*)alloc((size_t)EE*2*4);
    float* tab0 = (float*)alloc(256);
    float* tab1 = (float*)alloc(256);
    float* tab2 = (float*)alloc(256);

    // stage 0: input fc, emb0, edge-logit tables
    k_input_fc<<<dim3((NN*32)/256), dim3(256), 0, stream>>>(feats, fc_w, fc_b, nt);
    k_emb0<<<dim3((NN*32)/256), dim3(256), 0, stream>>>(nt, z);
    k_tab<<<dim3(RR*2), dim3(64), 0, stream>>>(eemb0, fce_w0, fce_b0, ae0, 2, tab0);
    k_tab<<<dim3(RR*2), dim3(64), 0, stream>>>(eemb1, fce_w1, fce_b1, ae1, 2, tab1);
    k_tab<<<dim3(RR*1), dim3(64), 0, stream>>>(eemb2, fce_w2, fce_b2, ae2, 1, tab2);

    // ---- layer 0 ----
    k_f0<<<dim3((NN*64)/256), dim3(256), 0, stream>>>(nt, w0, al0, ar0, fbuf, el, er);
    hipMemsetAsync(mkey, 0, (size_t)NN*2*4, stream);
    hipMemsetAsync(sbuf, 0, (size_t)NN*2*4, stream);
    hipMemsetAsync(r0,   0, (size_t)NN*192*4, stream);
    k_edge_max<<<dim3((EE*2)/256), dim3(256), 0, stream>>>(src, dst, etype, el, er, tab0, 2, ebuf, mkey);
    k_edge_expsum<<<dim3((EE*2)/256), dim3(256), 0, stream>>>(dst, 2, ebuf, mkey, sbuf);
    k_attn<<<dim3((EE*2)/256), dim3(256), 0, stream>>>(dst, 2, ebuf, sbuf, nullptr, a0b);
    k_scatter0<<<dim3((EE*64)/256), dim3(256), 0, stream>>>(src, dst, ebuf, fbuf, r0);
    k_final01<<<dim3(NN/2), dim3(192), 0, stream>>>(r0, b0, z, 32);   // r0 becomes h1

    // ---- layer 1 ----
    hipMemcpyAsync(r1, r0, (size_t)NN*192*4, hipMemcpyDeviceToDevice, stream); // residual init
    k_f1<<<dim3(NN), dim3(192), 0, stream>>>(r0, w1, fbuf);
    k_el1<<<dim3((NN*64)/256), dim3(256), 0, stream>>>(fbuf, al1, ar1, el, er);
    hipMemsetAsync(mkey, 0, (size_t)NN*2*4, stream);
    hipMemsetAsync(sbuf, 0, (size_t)NN*2*4, stream);
    k_edge_max<<<dim3((EE*2)/256), dim3(256), 0, stream>>>(src, dst, etype, el, er, tab1, 2, ebuf, mkey);
    k_edge_expsum<<<dim3((EE*2)/256), dim3(256), 0, stream>>>(dst, 2, ebuf, mkey, sbuf);
    k_attn<<<dim3((EE*2)/256), dim3(256), 0, stream>>>(dst, 2, ebuf, sbuf, a0b, nullptr);
    k_scatter1<<<dim3((EE*192)/256), dim3(256), 0, stream>>>(src, dst, ebuf, fbuf, r1);
    k_final01<<<dim3(NN/2), dim3(192), 0, stream>>>(r1, b1, z, 64);   // r1 becomes h2

    // ---- layer 2 ----
    k_f2res<<<dim3(NN/2), dim3(192), 0, stream>>>(r1, w2, resw2, fbuf, r2); // rst2 = residual
    k_el2<<<dim3((NN*64)/256), dim3(256), 0, stream>>>(fbuf, al2, ar2, el, er);
    hipMemsetAsync(mkey, 0, (size_t)NN*1*4, stream);
    hipMemsetAsync(sbuf, 0, (size_t)NN*1*4, stream);
    k_edge_max<<<dim3((EE*1)/256), dim3(256), 0, stream>>>(src, dst, etype, el, er, tab2, 1, ebuf, mkey);
    k_edge_expsum<<<dim3((EE*1)/256), dim3(256), 0, stream>>>(dst, 1, ebuf, mkey, sbuf);
    k_attn<<<dim3((EE*1)/256), dim3(256), 0, stream>>>(dst, 1, ebuf, sbuf, nullptr, nullptr);
    k_scatter2<<<dim3((EE*96)/256), dim3(256), 0, stream>>>(src, dst, ebuf, fbuf, r2);
    k_final2<<<dim3(NN/2), dim3(192), 0, stream>>>(r2, b2, z);

    // ---- DistMult scores ----
    k_distmult<<<dim3(BB/4), dim3(256), 0, stream>>>(z, Wdm, left, right, mid, out);
}